// Round 11
// baseline (5124.001 us; speedup 1.0000x reference)
//
#include <hip/hip_runtime.h>
#include <hip/hip_fp16.h>

// GRU-D 2-layer recurrent head, MI355X.
// Design R11 = R10 with the PIN_U4 macro fixed: the macro parameter was named
// `w`, so `(w).w` expanded to `(wxr1).wxr1` (macro params substitute even
// after `.`) -> compile error. Parameter renamed to V. Logic unchanged:
// R9 proved LDS pinning works (6.33->5.71ms = exact byte ratio) but the
// compiler rematerialized the 14 loop-invariant register-pinned weight loads
// (VGPR stayed 64, 8.2MB scratch). Opaque empty-asm defs force residency.
// Streamed: 1.17 -> 0.97 MB/step. Watch: VGPR_Count (expect 110-128),
// WRITE_SIZE (expect <=100KB; explosion = spill -> drop W0XR/XZ pins next).

#define BB  256
#define TT  512
#define DX  64
#define EE  32
#define DIN 96
#define HH  256

// packed half-weight offsets (in halves); region layout [K/32][256][4][8]
#define OFF_W0X_R 0        // K=96 regions: 3 segs * 8192
#define OFF_W0X_Z 24576
#define OFF_W0X_H 49152
#define OFF_W0H_R 73728    // K=256 regions: 8 segs * 8192
#define OFF_W0H_Z 139264
#define OFF_W0H_H 204800
#define OFF_W1X_R 270336
#define OFF_W1X_Z 335872
#define OFF_W1X_H 401408
#define OFF_W1H_R 466944
#define OFF_W1H_Z 532480
#define OFF_W1H_H 598016
#define PACK_TOTAL 663552  // halves = 1.33 MB

typedef _Float16 half2_t __attribute__((ext_vector_type(2)));

// Force a uint4 to stay materialized in VGPRs (defeat rematerialization of
// loop-invariant loads): opaque empty-asm def on each 32-bit component.
// NOTE: parameter must NOT be named x/y/z/w (macro params substitute after `.`).
#define PIN_U4(V) asm volatile("" : "+v"((V).x), "+v"((V).y), "+v"((V).z), "+v"((V).w))

__global__ void pack_weights(const float* __restrict__ Wr0, const float* __restrict__ Wz0,
                             const float* __restrict__ Wh0, const float* __restrict__ Wr1,
                             const float* __restrict__ Wz1, const float* __restrict__ Wh1,
                             __half* __restrict__ dst) {
  int idx = blockIdx.x * blockDim.x + threadIdx.x;
  if (idx >= PACK_TOTAL) return;
  const float* src;
  int row0, local;
  if (idx < 73728) {                       // x-part of layer0: K=96
    int r = idx / 24576; local = idx % 24576;
    src = (r == 0) ? Wr0 : (r == 1) ? Wz0 : Wh0;
    row0 = 0;
  } else {
    int q = (idx - 73728) / 65536; local = (idx - 73728) % 65536;
    if (q < 3)      { src = (q == 0) ? Wr0 : (q == 1) ? Wz0 : Wh0; row0 = 96;  }
    else if (q < 6) { src = (q == 3) ? Wr1 : (q == 4) ? Wz1 : Wh1; row0 = 0;   }
    else            { src = (q == 6) ? Wr1 : (q == 7) ? Wz1 : Wh1; row0 = 256; }
  }
  // region layout: [seg][j:256][s:4][i:8]; source K-row = seg*32 + s*8 + i
  int seg = local >> 13;
  int rem = local & 8191;
  int j   = rem >> 5;
  int s   = (rem >> 3) & 3;
  int i   = rem & 7;
  int row = row0 + seg * 32 + s * 8 + i;
  dst[idx] = __float2half(src[(size_t)row * HH + j]);
}

__device__ __forceinline__ float dot8(uint4 w, uint4 v, float acc) {
#if __has_builtin(__builtin_amdgcn_fdot2)
  union { uint4 u; half2_t h[4]; } W, V;
  W.u = w; V.u = v;
  acc = __builtin_amdgcn_fdot2(W.h[0], V.h[0], acc, false);
  acc = __builtin_amdgcn_fdot2(W.h[1], V.h[1], acc, false);
  acc = __builtin_amdgcn_fdot2(W.h[2], V.h[2], acc, false);
  acc = __builtin_amdgcn_fdot2(W.h[3], V.h[3], acc, false);
#else
  union { unsigned u; __half2 h; } cw, cv;
  float2 wf, vf;
  cw.u = w.x; cv.u = v.x; wf = __half22float2(cw.h); vf = __half22float2(cv.h);
  acc = fmaf(wf.x, vf.x, acc); acc = fmaf(wf.y, vf.y, acc);
  cw.u = w.y; cv.u = v.y; wf = __half22float2(cw.h); vf = __half22float2(cv.h);
  acc = fmaf(wf.x, vf.x, acc); acc = fmaf(wf.y, vf.y, acc);
  cw.u = w.z; cv.u = v.z; wf = __half22float2(cw.h); vf = __half22float2(cv.h);
  acc = fmaf(wf.x, vf.x, acc); acc = fmaf(wf.y, vf.y, acc);
  cw.u = w.w; cv.u = v.w; wf = __half22float2(cw.h); vf = __half22float2(cv.h);
  acc = fmaf(wf.x, vf.x, acc); acc = fmaf(wf.y, vf.y, acc);
#endif
  return acc;
}

__device__ __forceinline__ float kred(float a) {   // combine 4 K-split partials
  a += __shfl_xor(a, 1, 64);
  a += __shfl_xor(a, 2, 64);
  return a;
}

__device__ __forceinline__ float sigm(float x) { return 1.f / (1.f + __expf(-x)); }

__global__ __launch_bounds__(1024)
__attribute__((amdgpu_waves_per_eu(4, 4)))
void grud_fused(
    const float* __restrict__ x, const float* __restrict__ mask,
    const float* __restrict__ delta, const float* __restrict__ xl,
    const int* __restrict__ sidx, const float* __restrict__ emb,
    const float* __restrict__ gx0, const float* __restrict__ gh0,
    const float* __restrict__ br0, const float* __restrict__ bz0, const float* __restrict__ bh0,
    const float* __restrict__ br1, const float* __restrict__ bz1, const float* __restrict__ bh1,
    const float* __restrict__ Wp1, const float* __restrict__ bp1,
    const float* __restrict__ Wp2, const float* __restrict__ bp2,
    const __half* __restrict__ PW, float* __restrict__ out)
{
  const int b   = blockIdx.x;
  const int tid = threadIdx.x;
  const int j   = tid >> 2;      // hidden column 0..255
  const int s   = tid & 3;       // K-split 0..3
  const int s8  = s * 8;         // half-offset of this split's slice in a segment
  const int jb  = j * 4 + s;     // uint4 index within a segment

  __shared__ __align__(16) uint4 wlds[8192];   // 128 KiB: W0HH resident in LDS
  __shared__ __align__(16) __half xfh[DIN];    // x_filled (fp16, for dots)
  __shared__ __align__(16) __half hdech[HH];   // h_decay * h0_prev
  __shared__ __align__(16) __half rhh[HH];     // r * h_dec (reused by both layers)
  __shared__ __align__(16) __half h0h[HH];
  __shared__ __align__(16) __half h1h[HH];
  __shared__ float h1f[HH];
  __shared__ float p1f[HH];
  __shared__ float sdel;

  const float brj0 = br0[j], bzj0 = bz0[j], bhj0 = bh0[j];
  const float brj1 = br1[j], bzj1 = bz1[j], bhj1 = bh1[j];
  const float gh0j = gh0[j];
  float gx0j = 0.f;
  if (tid < DX) gx0j = gx0[tid];

  if (tid < HH) { h0h[tid] = __float2half(0.f); h1h[tid] = __float2half(0.f); }
  if (tid < EE) xfh[DX + tid] = __float2half(emb[(size_t)sidx[b] * EE + tid]); // const over t
  float h0j = 0.f, h1j = 0.f;

  const size_t xoff = (size_t)b * TT * DX;
  const uint4* W0XR = reinterpret_cast<const uint4*>(PW + OFF_W0X_R);
  const uint4* W0XZ = reinterpret_cast<const uint4*>(PW + OFF_W0X_Z);
  const uint4* W0XH = reinterpret_cast<const uint4*>(PW + OFF_W0X_H);
  const uint4* W0HR = reinterpret_cast<const uint4*>(PW + OFF_W0H_R);
  const uint4* W0HZ = reinterpret_cast<const uint4*>(PW + OFF_W0H_Z);
  const uint4* W0HH = reinterpret_cast<const uint4*>(PW + OFF_W0H_H);
  const uint4* W1XR = reinterpret_cast<const uint4*>(PW + OFF_W1X_R);
  const uint4* W1XZ = reinterpret_cast<const uint4*>(PW + OFF_W1X_Z);
  const uint4* W1XH = reinterpret_cast<const uint4*>(PW + OFF_W1X_H);
  const uint4* W1HR = reinterpret_cast<const uint4*>(PW + OFF_W1H_R);
  const uint4* W1HZ = reinterpret_cast<const uint4*>(PW + OFF_W1H_Z);
  const uint4* W1HH = reinterpret_cast<const uint4*>(PW + OFF_W1H_H);

  // ---- stage W0HH into LDS (once) ----
  #pragma unroll 2
  for (int seg = 0; seg < 8; ++seg) wlds[seg * 1024 + jb] = W0HH[seg * 1024 + jb];

  // ---- pin small weight set in registers; PIN_U4 defeats rematerialization ----
  uint4 wxr0 = W0XR[jb], wxr1 = W0XR[1024 + jb], wxr2 = W0XR[2048 + jb];
  uint4 wxz0 = W0XZ[jb], wxz1 = W0XZ[1024 + jb], wxz2 = W0XZ[2048 + jb];
  uint4 whh0 = W1HH[jb],            whh1 = W1HH[1024 + jb];
  uint4 whh2 = W1HH[2 * 1024 + jb], whh3 = W1HH[3 * 1024 + jb];
  uint4 whh4 = W1HH[4 * 1024 + jb], whh5 = W1HH[5 * 1024 + jb];
  uint4 whh6 = W1HH[6 * 1024 + jb], whh7 = W1HH[7 * 1024 + jb];
  PIN_U4(wxr0); PIN_U4(wxr1); PIN_U4(wxr2);
  PIN_U4(wxz0); PIN_U4(wxz1); PIN_U4(wxz2);
  PIN_U4(whh0); PIN_U4(whh1); PIN_U4(whh2); PIN_U4(whh3);
  PIN_U4(whh4); PIN_U4(whh5); PIN_U4(whh6); PIN_U4(whh7);

  // prefetch t=0 inputs into registers
  float xv = 0.f, mv = 0.f, dv = 0.f, xlv = 0.f;
  if (tid < DX) {
    size_t a = xoff + tid;
    xv = x[a]; mv = mask[a]; dv = delta[a]; xlv = xl[a];
  }
  __syncthreads();

  for (int t = 0; t < TT; ++t) {
    // ---- P0: x_filled (wave 0, from prefetched regs) + mean-delta scalar ----
    if (tid < DX) {
      float xd = __expf(-fmaxf(dv * gx0j, 0.f)) * xlv;
      xfh[tid] = __float2half(mv > 0.f ? xv : xd);
      float ssum = dv;
      #pragma unroll
      for (int o = 32; o > 0; o >>= 1) ssum += __shfl_down(ssum, o, 64);
      if (tid == 0) sdel = ssum * (1.f / 96.f);
    }
    __syncthreads();
    // ---- P1: h_dec = exp(-relu(sdel*gh0)) * h0 (redundant across s) ----
    float hd = __expf(-fmaxf(sdel * gh0j, 0.f));
    float hdecj = hd * h0j;
    if (s == 0) hdech[j] = __float2half(hdecj);
    __syncthreads();

    // ---- prefetch inputs for t+1 (independent; compiler schedules early) ----
    if (tid < DX && t + 1 < TT) {
      size_t a = xoff + (size_t)(t + 1) * DX + tid;
      xv = x[a]; mv = mask[a]; dv = delta[a]; xlv = xl[a];
    }

    // ---- P2: layer0 r,z pre-acts + x-part of h_tilde ----
    float ar = 0.f, az = 0.f, ah = 0.f;
    {  // x-part, hand-unrolled: R,Z from pinned regs; H streamed
      uint4 v0 = *reinterpret_cast<const uint4*>(xfh + s8);
      uint4 v1 = *reinterpret_cast<const uint4*>(xfh + 32 + s8);
      uint4 v2 = *reinterpret_cast<const uint4*>(xfh + 64 + s8);
      ar = dot8(wxr0, v0, ar); az = dot8(wxz0, v0, az); ah = dot8(W0XH[jb], v0, ah);
      ar = dot8(wxr1, v1, ar); az = dot8(wxz1, v1, az); ah = dot8(W0XH[1024 + jb], v1, ah);
      ar = dot8(wxr2, v2, ar); az = dot8(wxz2, v2, az); ah = dot8(W0XH[2048 + jb], v2, ah);
    }
    #pragma unroll 4
    for (int seg = 0; seg < 8; ++seg) {
      uint4 v = *reinterpret_cast<const uint4*>(hdech + seg * 32 + s8);
      int wi = seg * 1024 + jb;
      ar = dot8(W0HR[wi], v, ar);
      az = dot8(W0HZ[wi], v, az);
    }
    ar = kred(ar) + brj0;
    az = kred(az) + bzj0;
    float r = sigm(ar);
    float z = sigm(az);
    if (s == 0) rhh[j] = __float2half(r * hdecj);
    __syncthreads();
    // ---- P3: layer0 h_tilde from LDS-resident W0HH (no global loads) ----
    #pragma unroll 4
    for (int seg = 0; seg < 8; ++seg) {
      uint4 v = *reinterpret_cast<const uint4*>(rhh + seg * 32 + s8);
      ah = dot8(wlds[seg * 1024 + jb], v, ah);
    }
    ah = kred(ah) + bhj0;
    float ht = tanhf(ah);
    h0j = (1.f - z) * hdecj + z * ht;
    if (s == 0) h0h[j] = __float2half(h0j);
    __syncthreads();
    // ---- P4: layer1 r,z pre-acts + h0-part of h_tilde (streamed) ----
    float ar1 = 0.f, az1 = 0.f, ah1 = 0.f;
    #pragma unroll 2
    for (int seg = 0; seg < 8; ++seg) {
      uint4 v0 = *reinterpret_cast<const uint4*>(h0h + seg * 32 + s8);
      uint4 v1 = *reinterpret_cast<const uint4*>(h1h + seg * 32 + s8);
      int wi = seg * 1024 + jb;
      ar1 = dot8(W1XR[wi], v0, ar1);
      az1 = dot8(W1XZ[wi], v0, az1);
      ah1 = dot8(W1XH[wi], v0, ah1);
      ar1 = dot8(W1HR[wi], v1, ar1);
      az1 = dot8(W1HZ[wi], v1, az1);
    }
    ar1 = kred(ar1) + brj1;
    az1 = kred(az1) + bzj1;
    float r1 = sigm(ar1);
    float z1 = sigm(az1);
    if (s == 0) rhh[j] = __float2half(r1 * h1j);
    __syncthreads();
    // ---- P5: layer1 h_tilde from register-resident W1HH (no loads at all) ----
    ah1 = dot8(whh0, *reinterpret_cast<const uint4*>(rhh + 0 * 32 + s8), ah1);
    ah1 = dot8(whh1, *reinterpret_cast<const uint4*>(rhh + 1 * 32 + s8), ah1);
    ah1 = dot8(whh2, *reinterpret_cast<const uint4*>(rhh + 2 * 32 + s8), ah1);
    ah1 = dot8(whh3, *reinterpret_cast<const uint4*>(rhh + 3 * 32 + s8), ah1);
    ah1 = dot8(whh4, *reinterpret_cast<const uint4*>(rhh + 4 * 32 + s8), ah1);
    ah1 = dot8(whh5, *reinterpret_cast<const uint4*>(rhh + 5 * 32 + s8), ah1);
    ah1 = dot8(whh6, *reinterpret_cast<const uint4*>(rhh + 6 * 32 + s8), ah1);
    ah1 = dot8(whh7, *reinterpret_cast<const uint4*>(rhh + 7 * 32 + s8), ah1);
    ah1 = kred(ah1) + bhj1;
    float ht1 = tanhf(ah1);
    h1j = (1.f - z1) * h1j + z1 * ht1;
    if (s == 0) h1h[j] = __float2half(h1j);
  }

  // ---- head: out = relu(h1 @ Wp1 + bp1) @ Wp2 + bp2, fp32, K-split too ----
  if (s == 0) h1f[j] = h1j;
  __syncthreads();
  {
    float a1 = 0.f;
    int k0 = s * 64;
    #pragma unroll 8
    for (int k = 0; k < 64; ++k) a1 = fmaf(h1f[k0 + k], Wp1[(size_t)(k0 + k) * HH + j], a1);
    a1 = kred(a1) + bp1[j];
    if (s == 0) p1f[j] = fmaxf(a1, 0.f);
  }
  __syncthreads();
  if (tid < 192) {
    int jo = tid >> 2, so = tid & 3;   // 48 outputs x 4 splits
    float o = 0.f;
    int k0 = so * 64;
    #pragma unroll 8
    for (int k = 0; k < 64; ++k) o = fmaf(p1f[k0 + k], Wp2[(size_t)(k0 + k) * 48 + jo], o);
    o += __shfl_xor(o, 1, 64);
    o += __shfl_xor(o, 2, 64);
    if (so == 0) out[(size_t)b * 48 + jo] = o + bp2[jo];
  }
}

extern "C" void kernel_launch(void* const* d_in, const int* in_sizes, int n_in,
                              void* d_out, int out_size, void* d_ws, size_t ws_size,
                              hipStream_t stream) {
  const float* x    = (const float*)d_in[0];
  const float* mask = (const float*)d_in[1];
  const float* delta= (const float*)d_in[2];
  const float* xl   = (const float*)d_in[3];
  const int*   sidx = (const int*)d_in[4];
  const float* emb  = (const float*)d_in[5];
  const float* gx0  = (const float*)d_in[6];
  const float* gh0  = (const float*)d_in[7];
  const float* Wr0  = (const float*)d_in[8];
  const float* br0  = (const float*)d_in[9];
  const float* Wz0  = (const float*)d_in[10];
  const float* bz0  = (const float*)d_in[11];
  const float* Wh0  = (const float*)d_in[12];
  const float* bh0  = (const float*)d_in[13];
  // d_in[14]=gx1, d_in[15]=gh1: mathematically inert (layer1 delta==0)
  const float* Wr1  = (const float*)d_in[16];
  const float* br1  = (const float*)d_in[17];
  const float* Wz1  = (const float*)d_in[18];
  const float* bz1  = (const float*)d_in[19];
  const float* Wh1  = (const float*)d_in[20];
  const float* bh1  = (const float*)d_in[21];
  const float* Wp1  = (const float*)d_in[22];
  const float* bp1  = (const float*)d_in[23];
  const float* Wp2  = (const float*)d_in[24];
  const float* bp2  = (const float*)d_in[25];
  __half* PW = (__half*)d_ws;          // 1.33 MB used; re-packed every call
  float* out = (float*)d_out;

  hipLaunchKernelGGL(pack_weights, dim3((PACK_TOTAL + 255) / 256), dim3(256), 0, stream,
                     Wr0, Wz0, Wh0, Wr1, Wz1, Wh1, PW);
  hipLaunchKernelGGL(grud_fused, dim3(BB), dim3(1024), 0, stream,
                     x, mask, delta, xl, sidx, emb, gx0, gh0,
                     br0, bz0, bh0, br1, bz1, bh1, Wp1, bp1, Wp2, bp2, PW, out);
}

// Round 12
// 3592.662 us; speedup vs baseline: 1.4262x; 1.4262x over previous
//
#include <hip/hip_runtime.h>
#include <hip/hip_fp16.h>

// GRU-D 2-layer recurrent head, MI355X.
// Design R12: producer-consumer CU pairing. R9-R11 proved the single-block
// streaming design is pinned at 106 GB/s/CU (rate constant across byte loads)
// and the compiler won't hold >64 VGPR (register pinning = dead lever).
// Structure: pair (A=bid, B=bid+128), 2 batches per pair (2*pair, 2*pair+1).
//  A: layer-0 for both batches; streams W0XR/Z/H + W0HR/Z + W1XH (528 KB/step),
//     pins W0HH in LDS (128 KB). Sends h0 (fp16) + W1XH.h0 partial (fp32).
//  B: layer-1 + head; streams W1XR/Z + W1HR/Z (512 KB/step), pins W1HH in LDS.
// Messages: depth-4 ring in d_ws, relaxed agent-scope atomics (LLC-coherent,
// no L2-invalidating fences), exact-match flags (0xAA-poison safe), consume
// flags for backpressure, bounded spins (deadlock -> wrong answer, not hang).
// Both batches g-fused per thread: each weight load feeds 2 dot chains.
// Per-CU streamed bytes 1170 -> ~520 KB/step => predict ~3.0-3.7 ms.

#define BB   256
#define TT   512
#define DX   64
#define EE   32
#define HH   256
#define RING 4

// packed half-weight offsets (in halves); region layout [seg][256][4][8] (unchanged)
#define OFF_W0X_R 0
#define OFF_W0X_Z 24576
#define OFF_W0X_H 49152
#define OFF_W0H_R 73728
#define OFF_W0H_Z 139264
#define OFF_W0H_H 204800
#define OFF_W1X_R 270336
#define OFF_W1X_Z 335872
#define OFF_W1X_H 401408
#define OFF_W1H_R 466944
#define OFF_W1H_Z 532480
#define OFF_W1H_H 598016
#define PACK_TOTAL 663552

// d_ws byte offsets: PW | msg ring | flags | cflags
#define MSG_OFF   1327104                 // = PACK_TOTAL*2
#define MSG_U32   768                     // 256 u32 (h0 2x256 fp16) + 512 u32 (ah1x 2x256 fp32)
#define FLAG_OFF  (MSG_OFF + 128*RING*MSG_U32*4)
#define CFLAG_OFF (FLAG_OFF + 128*RING*4)

typedef _Float16 half2_t __attribute__((ext_vector_type(2)));

__global__ void pack_weights(const float* __restrict__ Wr0, const float* __restrict__ Wz0,
                             const float* __restrict__ Wh0, const float* __restrict__ Wr1,
                             const float* __restrict__ Wz1, const float* __restrict__ Wh1,
                             __half* __restrict__ dst) {
  int idx = blockIdx.x * blockDim.x + threadIdx.x;
  if (idx >= PACK_TOTAL) return;
  const float* src;
  int row0, local;
  if (idx < 73728) {                       // x-part of layer0: K=96
    int r = idx / 24576; local = idx % 24576;
    src = (r == 0) ? Wr0 : (r == 1) ? Wz0 : Wh0;
    row0 = 0;
  } else {
    int q = (idx - 73728) / 65536; local = (idx - 73728) % 65536;
    if (q < 3)      { src = (q == 0) ? Wr0 : (q == 1) ? Wz0 : Wh0; row0 = 96;  }
    else if (q < 6) { src = (q == 3) ? Wr1 : (q == 4) ? Wz1 : Wh1; row0 = 0;   }
    else            { src = (q == 6) ? Wr1 : (q == 7) ? Wz1 : Wh1; row0 = 256; }
  }
  int seg = local >> 13;
  int rem = local & 8191;
  int j   = rem >> 5;
  int s   = (rem >> 3) & 3;
  int i   = rem & 7;
  int row = row0 + seg * 32 + s * 8 + i;
  dst[idx] = __float2half(src[(size_t)row * HH + j]);
}

__device__ __forceinline__ float dot8(uint4 w, uint4 v, float acc) {
#if __has_builtin(__builtin_amdgcn_fdot2)
  union { uint4 u; half2_t h[4]; } W, V;
  W.u = w; V.u = v;
  acc = __builtin_amdgcn_fdot2(W.h[0], V.h[0], acc, false);
  acc = __builtin_amdgcn_fdot2(W.h[1], V.h[1], acc, false);
  acc = __builtin_amdgcn_fdot2(W.h[2], V.h[2], acc, false);
  acc = __builtin_amdgcn_fdot2(W.h[3], V.h[3], acc, false);
#else
  union { unsigned u; __half2 h; } cw, cv;
  float2 wf, vf;
  cw.u = w.x; cv.u = v.x; wf = __half22float2(cw.h); vf = __half22float2(cv.h);
  acc = fmaf(wf.x, vf.x, acc); acc = fmaf(wf.y, vf.y, acc);
  cw.u = w.y; cv.u = v.y; wf = __half22float2(cw.h); vf = __half22float2(cv.h);
  acc = fmaf(wf.x, vf.x, acc); acc = fmaf(wf.y, vf.y, acc);
  cw.u = w.z; cv.u = v.z; wf = __half22float2(cw.h); vf = __half22float2(cv.h);
  acc = fmaf(wf.x, vf.x, acc); acc = fmaf(wf.y, vf.y, acc);
  cw.u = w.w; cv.u = v.w; wf = __half22float2(cw.h); vf = __half22float2(cv.h);
  acc = fmaf(wf.x, vf.x, acc); acc = fmaf(wf.y, vf.y, acc);
#endif
  return acc;
}

__device__ __forceinline__ float kred(float a) {
  a += __shfl_xor(a, 1, 64);
  a += __shfl_xor(a, 2, 64);
  return a;
}

__device__ __forceinline__ float sigm(float x) { return 1.f / (1.f + __expf(-x)); }

// bounded exact-match spin on an agent-scope flag (0xAA poison never matches)
__device__ __forceinline__ void spin_eq(uint32_t* p, uint32_t want) {
  for (int it = 0; it < 1000000; ++it) {
    if (__hip_atomic_load(p, __ATOMIC_RELAXED, __HIP_MEMORY_SCOPE_AGENT) == want) return;
    __builtin_amdgcn_s_sleep(1);
  }
}

__global__ __launch_bounds__(1024)
__attribute__((amdgpu_waves_per_eu(4, 4)))
void grud_pipe(const float* __restrict__ x, const float* __restrict__ mask,
               const float* __restrict__ delta, const float* __restrict__ xl,
               const int* __restrict__ sidx, const float* __restrict__ emb,
               const float* __restrict__ gx0, const float* __restrict__ gh0,
               const float* __restrict__ br0, const float* __restrict__ bz0,
               const float* __restrict__ bh0, const float* __restrict__ br1,
               const float* __restrict__ bz1, const float* __restrict__ bh1,
               const float* __restrict__ Wp1, const float* __restrict__ bp1,
               const float* __restrict__ Wp2, const float* __restrict__ bp2,
               const __half* __restrict__ PW, uint32_t* wsu, float* __restrict__ out)
{
  const int bid = blockIdx.x;
  const bool isA = bid < 128;
  const int pair = isA ? bid : (bid - 128);
  const int tid = threadIdx.x;
  const int j = tid >> 2, s = tid & 3, s8 = s * 8, jb = j * 4 + s;

  uint32_t* msgbase = wsu + (MSG_OFF >> 2) + (size_t)pair * (RING * MSG_U32);
  uint32_t* flag    = wsu + (FLAG_OFF >> 2) + pair * RING;
  uint32_t* cflag   = wsu + (CFLAG_OFF >> 2) + pair * RING;

  __shared__ __align__(16) uint4  wlds[8192];   // 128 KiB: W0HH (A) / W1HH (B)
  __shared__ __align__(16) __half xfh[2][96];
  __shared__ __align__(16) __half hdech[2][256];
  __shared__ __align__(16) __half rhh[2][256];
  __shared__ __align__(16) __half h0h[2][256];
  __shared__ __align__(16) __half h0c[2][256];
  __shared__ __align__(16) __half h1h[2][256];
  __shared__ __align__(16) float  fbuf[2][256]; // ah1x in loop; h1 fp32 in head
  __shared__ float p1f[256];
  __shared__ float sdel[2];

  if (isA) {
    const uint4* W0XR = (const uint4*)(PW + OFF_W0X_R);
    const uint4* W0XZ = (const uint4*)(PW + OFF_W0X_Z);
    const uint4* W0XH = (const uint4*)(PW + OFF_W0X_H);
    const uint4* W0HR = (const uint4*)(PW + OFF_W0H_R);
    const uint4* W0HZ = (const uint4*)(PW + OFF_W0H_Z);
    const uint4* W0HH = (const uint4*)(PW + OFF_W0H_H);
    const uint4* W1XH = (const uint4*)(PW + OFF_W1X_H);
    #pragma unroll 2
    for (int seg = 0; seg < 8; ++seg) wlds[seg * 1024 + jb] = W0HH[seg * 1024 + jb];

    const float brj0 = br0[j], bzj0 = bz0[j], bhj0 = bh0[j];
    const float gh0j = gh0[j];
    float h0j0 = 0.f, h0j1 = 0.f;
    if (tid < 512) { int g = tid >> 8, k = tid & 255; h0h[g][k] = __float2half(0.f); }
    if (tid < 64)  { int g = tid >> 5, e = tid & 31;
                     xfh[g][DX + e] = __float2half(emb[(size_t)sidx[2 * pair + g] * EE + e]); }
    float gx0k = 0.f;
    if (tid < 128) gx0k = gx0[tid & 63];
    const size_t xb0 = (size_t)(2 * pair) * TT * DX, xb1 = (size_t)(2 * pair + 1) * TT * DX;
    float xv = 0, mv = 0, dv = 0, xlv = 0;
    if (tid < 128) { size_t a = (tid < 64 ? xb0 : xb1) + (tid & 63);
                     xv = x[a]; mv = mask[a]; dv = delta[a]; xlv = xl[a]; }
    __syncthreads();

    for (int t = 0; t < TT; ++t) {
      const int slot = t & (RING - 1);
      if (tid == 0 && t >= RING) spin_eq(&cflag[slot], (uint32_t)(t - RING + 1));
      // P0: x_filled + mean-delta (2 waves, one per batch)
      if (tid < 128) {
        int g = tid >> 6;
        float xd = __expf(-fmaxf(dv * gx0k, 0.f)) * xlv;
        xfh[g][tid & 63] = __float2half(mv > 0.f ? xv : xd);
        float ssum = dv;
        #pragma unroll
        for (int o = 32; o > 0; o >>= 1) ssum += __shfl_down(ssum, o, 64);
        if ((tid & 63) == 0) sdel[g] = ssum * (1.f / 96.f);
      }
      __syncthreads();
      // P1: fp32 hdec per thread (state path stays fp32, as R4-R11)
      float hd0 = __expf(-fmaxf(sdel[0] * gh0j, 0.f)) * h0j0;
      float hd1 = __expf(-fmaxf(sdel[1] * gh0j, 0.f)) * h0j1;
      if (s == 0) { hdech[0][j] = __float2half(hd0); hdech[1][j] = __float2half(hd1); }
      __syncthreads();
      // prefetch next-t inputs
      if (tid < 128 && t + 1 < TT) {
        size_t a = (tid < 64 ? xb0 : xb1) + (size_t)(t + 1) * DX + (tid & 63);
        xv = x[a]; mv = mask[a]; dv = delta[a]; xlv = xl[a];
      }
      // P2: L0 gates (both batches share each weight load)
      float ar0 = 0, ar1v = 0, az0 = 0, az1v = 0, ah0 = 0, ah1v = 0;
      #pragma unroll
      for (int seg = 0; seg < 3; ++seg) {
        uint4 v0 = *(const uint4*)(&xfh[0][seg * 32 + s8]);
        uint4 v1 = *(const uint4*)(&xfh[1][seg * 32 + s8]);
        uint4 wr = W0XR[seg * 1024 + jb], wz = W0XZ[seg * 1024 + jb], wh = W0XH[seg * 1024 + jb];
        ar0 = dot8(wr, v0, ar0); ar1v = dot8(wr, v1, ar1v);
        az0 = dot8(wz, v0, az0); az1v = dot8(wz, v1, az1v);
        ah0 = dot8(wh, v0, ah0); ah1v = dot8(wh, v1, ah1v);
      }
      #pragma unroll 2
      for (int seg = 0; seg < 8; ++seg) {
        uint4 v0 = *(const uint4*)(&hdech[0][seg * 32 + s8]);
        uint4 v1 = *(const uint4*)(&hdech[1][seg * 32 + s8]);
        uint4 wr = W0HR[seg * 1024 + jb], wz = W0HZ[seg * 1024 + jb];
        ar0 = dot8(wr, v0, ar0); ar1v = dot8(wr, v1, ar1v);
        az0 = dot8(wz, v0, az0); az1v = dot8(wz, v1, az1v);
      }
      ar0 = kred(ar0) + brj0; ar1v = kred(ar1v) + brj0;
      az0 = kred(az0) + bzj0; az1v = kred(az1v) + bzj0;
      float r0 = sigm(ar0), r1g = sigm(ar1v), z0 = sigm(az0), z1g = sigm(az1v);
      if (s == 0) { rhh[0][j] = __float2half(r0 * hd0); rhh[1][j] = __float2half(r1g * hd1); }
      __syncthreads();
      // P3: h_tilde from LDS-resident W0HH; h0 update
      #pragma unroll 2
      for (int seg = 0; seg < 8; ++seg) {
        uint4 w  = wlds[seg * 1024 + jb];
        uint4 v0 = *(const uint4*)(&rhh[0][seg * 32 + s8]);
        uint4 v1 = *(const uint4*)(&rhh[1][seg * 32 + s8]);
        ah0 = dot8(w, v0, ah0); ah1v = dot8(w, v1, ah1v);
      }
      ah0 = kred(ah0) + bhj0; ah1v = kred(ah1v) + bhj0;
      h0j0 = (1.f - z0) * hd0 + z0 * tanhf(ah0);
      h0j1 = (1.f - z1g) * hd1 + z1g * tanhf(ah1v);
      if (s == 0) { h0h[0][j] = __float2half(h0j0); h0h[1][j] = __float2half(h0j1); }
      __syncthreads();
      // P3b: ah1x = W1XH . h0 (full kred'd partial for B), fp32
      float ax0 = 0.f, ax1 = 0.f;
      #pragma unroll 2
      for (int seg = 0; seg < 8; ++seg) {
        uint4 w  = W1XH[seg * 1024 + jb];
        uint4 v0 = *(const uint4*)(&h0h[0][seg * 32 + s8]);
        uint4 v1 = *(const uint4*)(&h0h[1][seg * 32 + s8]);
        ax0 = dot8(w, v0, ax0); ax1 = dot8(w, v1, ax1);
      }
      ax0 = kred(ax0); ax1 = kred(ax1);
      // message: h0 (256 u32 of fp16x2) + partials (512 u32 fp32)
      uint32_t* msg = msgbase + slot * MSG_U32;
      if (s == 0) {
        __hip_atomic_store(msg + 256 + j, __float_as_uint(ax0), __ATOMIC_RELAXED, __HIP_MEMORY_SCOPE_AGENT);
        __hip_atomic_store(msg + 512 + j, __float_as_uint(ax1), __ATOMIC_RELAXED, __HIP_MEMORY_SCOPE_AGENT);
      }
      if (tid < 256)
        __hip_atomic_store(msg + tid, ((const uint32_t*)h0h)[tid], __ATOMIC_RELAXED, __HIP_MEMORY_SCOPE_AGENT);
      __syncthreads();   // compiler drains vmcnt before s_barrier -> stores complete
      if (tid == 0)
        __hip_atomic_store(&flag[slot], (uint32_t)(t + 1), __ATOMIC_RELAXED, __HIP_MEMORY_SCOPE_AGENT);
    }
    // A-blocks: no head, done.
  } else {
    const uint4* W1XR = (const uint4*)(PW + OFF_W1X_R);
    const uint4* W1XZ = (const uint4*)(PW + OFF_W1X_Z);
    const uint4* W1HR = (const uint4*)(PW + OFF_W1H_R);
    const uint4* W1HZ = (const uint4*)(PW + OFF_W1H_Z);
    const uint4* W1HH = (const uint4*)(PW + OFF_W1H_H);
    #pragma unroll 2
    for (int seg = 0; seg < 8; ++seg) wlds[seg * 1024 + jb] = W1HH[seg * 1024 + jb];
    const float brj1 = br1[j], bzj1 = bz1[j], bhj1 = bh1[j];
    float h1j0 = 0.f, h1j1 = 0.f;
    if (tid < 512) { int g = tid >> 8, k = tid & 255; h1h[g][k] = __float2half(0.f); }
    __syncthreads();

    for (int t = 0; t < TT; ++t) {
      const int slot = t & (RING - 1);
      if (tid == 0) spin_eq(&flag[slot], (uint32_t)(t + 1));
      __syncthreads();
      uint32_t* msg = msgbase + slot * MSG_U32;
      if (tid < 256)
        ((uint32_t*)h0c)[tid] = __hip_atomic_load(msg + tid, __ATOMIC_RELAXED, __HIP_MEMORY_SCOPE_AGENT);
      else if (tid < 768) {
        int idx = tid - 256;
        fbuf[idx >> 8][idx & 255] =
            __uint_as_float(__hip_atomic_load(msg + tid, __ATOMIC_RELAXED, __HIP_MEMORY_SCOPE_AGENT));
      }
      __syncthreads();   // loads landed in LDS
      if (tid == 0)
        __hip_atomic_store(&cflag[slot], (uint32_t)(t + 1), __ATOMIC_RELAXED, __HIP_MEMORY_SCOPE_AGENT);
      // L1 gates
      float ar0 = 0, ar1v = 0, az0 = 0, az1v = 0;
      #pragma unroll 2
      for (int seg = 0; seg < 8; ++seg) {
        uint4 u0 = *(const uint4*)(&h0c[0][seg * 32 + s8]);
        uint4 u1 = *(const uint4*)(&h0c[1][seg * 32 + s8]);
        uint4 v0 = *(const uint4*)(&h1h[0][seg * 32 + s8]);
        uint4 v1 = *(const uint4*)(&h1h[1][seg * 32 + s8]);
        uint4 wxr = W1XR[seg * 1024 + jb], wxz = W1XZ[seg * 1024 + jb];
        uint4 whr = W1HR[seg * 1024 + jb], whz = W1HZ[seg * 1024 + jb];
        ar0 = dot8(wxr, u0, ar0);  ar0 = dot8(whr, v0, ar0);
        ar1v = dot8(wxr, u1, ar1v); ar1v = dot8(whr, v1, ar1v);
        az0 = dot8(wxz, u0, az0);  az0 = dot8(whz, v0, az0);
        az1v = dot8(wxz, u1, az1v); az1v = dot8(whz, v1, az1v);
      }
      ar0 = kred(ar0) + brj1; ar1v = kred(ar1v) + brj1;
      az0 = kred(az0) + bzj1; az1v = kred(az1v) + bzj1;
      float r0 = sigm(ar0), r1g = sigm(ar1v), z0 = sigm(az0), z1g = sigm(az1v);
      if (s == 0) { rhh[0][j] = __float2half(r0 * h1j0); rhh[1][j] = __float2half(r1g * h1j1); }
      __syncthreads();
      // P5: h_tilde = ah1x (from A) + W1HH(LDS).rhh ; h1 update
      float p0 = 0.f, p1 = 0.f;
      #pragma unroll 2
      for (int seg = 0; seg < 8; ++seg) {
        uint4 w  = wlds[seg * 1024 + jb];
        uint4 v0 = *(const uint4*)(&rhh[0][seg * 32 + s8]);
        uint4 v1 = *(const uint4*)(&rhh[1][seg * 32 + s8]);
        p0 = dot8(w, v0, p0); p1 = dot8(w, v1, p1);
      }
      p0 = kred(p0); p1 = kred(p1);
      float ahf0 = fbuf[0][j] + p0 + bhj1;
      float ahf1 = fbuf[1][j] + p1 + bhj1;
      h1j0 = (1.f - z0) * h1j0 + z0 * tanhf(ahf0);
      h1j1 = (1.f - z1g) * h1j1 + z1g * tanhf(ahf1);
      if (s == 0) { h1h[0][j] = __float2half(h1j0); h1h[1][j] = __float2half(h1j1); }
      // next iteration's copy-barrier orders h1h/rhh/fbuf reuse
    }

    // head for both batches (fp32)
    if (s == 0) { fbuf[0][j] = h1j0; fbuf[1][j] = h1j1; }
    __syncthreads();
    for (int g = 0; g < 2; ++g) {
      float a1 = 0.f; int k0 = s * 64;
      #pragma unroll 8
      for (int k = 0; k < 64; ++k) a1 = fmaf(fbuf[g][k0 + k], Wp1[(size_t)(k0 + k) * HH + j], a1);
      a1 = kred(a1) + bp1[j];
      if (s == 0) p1f[j] = fmaxf(a1, 0.f);
      __syncthreads();
      if (tid < 192) {
        int jo = tid >> 2, so = tid & 3; float o = 0.f; int kk0 = so * 64;
        #pragma unroll 8
        for (int k = 0; k < 64; ++k) o = fmaf(p1f[kk0 + k], Wp2[(size_t)(kk0 + k) * 48 + jo], o);
        o += __shfl_xor(o, 1, 64);
        o += __shfl_xor(o, 2, 64);
        if (so == 0) out[(size_t)(2 * pair + g) * 48 + jo] = o + bp2[jo];
      }
      __syncthreads();
    }
  }
}

extern "C" void kernel_launch(void* const* d_in, const int* in_sizes, int n_in,
                              void* d_out, int out_size, void* d_ws, size_t ws_size,
                              hipStream_t stream) {
  const float* x    = (const float*)d_in[0];
  const float* mask = (const float*)d_in[1];
  const float* delta= (const float*)d_in[2];
  const float* xl   = (const float*)d_in[3];
  const int*   sidx = (const int*)d_in[4];
  const float* emb  = (const float*)d_in[5];
  const float* gx0  = (const float*)d_in[6];
  const float* gh0  = (const float*)d_in[7];
  const float* Wr0  = (const float*)d_in[8];
  const float* br0  = (const float*)d_in[9];
  const float* Wz0  = (const float*)d_in[10];
  const float* bz0  = (const float*)d_in[11];
  const float* Wh0  = (const float*)d_in[12];
  const float* bh0  = (const float*)d_in[13];
  // d_in[14]=gx1, d_in[15]=gh1: mathematically inert (layer1 delta==0)
  const float* Wr1  = (const float*)d_in[16];
  const float* br1  = (const float*)d_in[17];
  const float* Wz1  = (const float*)d_in[18];
  const float* bz1  = (const float*)d_in[19];
  const float* Wh1  = (const float*)d_in[20];
  const float* bh1  = (const float*)d_in[21];
  const float* Wp1  = (const float*)d_in[22];
  const float* bp1  = (const float*)d_in[23];
  const float* Wp2  = (const float*)d_in[24];
  const float* bp2  = (const float*)d_in[25];
  __half*   PW  = (__half*)d_ws;          // first 1.33 MB
  uint32_t* wsu = (uint32_t*)d_ws;        // mailboxes beyond PW (total ~2.8 MB)
  float* out = (float*)d_out;

  hipLaunchKernelGGL(pack_weights, dim3((PACK_TOTAL + 255) / 256), dim3(256), 0, stream,
                     Wr0, Wz0, Wh0, Wr1, Wz1, Wh1, PW);
  hipLaunchKernelGGL(grud_pipe, dim3(BB), dim3(1024), 0, stream,
                     x, mask, delta, xl, sidx, emb, gx0, gh0,
                     br0, bz0, bh0, br1, bz1, bh1, Wp1, bp1, Wp2, bp2, PW, wsu, out);
}

// Round 13
// 3491.907 us; speedup vs baseline: 1.4674x; 1.0289x over previous
//
#include <hip/hip_runtime.h>
#include <hip/hip_fp16.h>

// GRU-D 2-layer recurrent head, MI355X.
// Design R13 = R12 pipeline + critical-path (A-block) trimming:
//  - fast transcendentals: tanh via exp+v_rcp (~10 instr vs ~40 libm),
//    sigmoid via v_rcp (R12: VALUBusy 57% = 4.5us/step but dot floor is only
//    1.1us -> ~3us/step of non-dot VALU, largely libm + phase overhead)
//  - A: P0/P1 barriers merged via redundant per-wave mean-delta (2 broadcast
//    loads + shfl reduce), 6 -> 5 barriers/step
//  - A: 9 x-part weight loads issued BEFORE the merged barrier (vmcnt drain
//    at the barrier completes them under P0 compute); input prefetch moved
//    after the barrier (in flight under P2 dots)
//  - B: h-dependent gate dots (W1HR/W1HZ, 256KB/step) issued BEFORE the flag
//    spin -> B's streaming overlaps A's production; B never critical.
// Watch: WRITE_SIZE ~200KB (balloon = early-load spill -> revert),
// absmax <= ~1e-3 (worse -> revert fast tanh).

#define BB   256
#define TT   512
#define DX   64
#define EE   32
#define HH   256
#define RING 4

#define OFF_W0X_R 0
#define OFF_W0X_Z 24576
#define OFF_W0X_H 49152
#define OFF_W0H_R 73728
#define OFF_W0H_Z 139264
#define OFF_W0H_H 204800
#define OFF_W1X_R 270336
#define OFF_W1X_Z 335872
#define OFF_W1X_H 401408
#define OFF_W1H_R 466944
#define OFF_W1H_Z 532480
#define OFF_W1H_H 598016
#define PACK_TOTAL 663552

#define MSG_OFF   1327104
#define MSG_U32   768
#define FLAG_OFF  (MSG_OFF + 128*RING*MSG_U32*4)
#define CFLAG_OFF (FLAG_OFF + 128*RING*4)

typedef _Float16 half2_t __attribute__((ext_vector_type(2)));

__global__ void pack_weights(const float* __restrict__ Wr0, const float* __restrict__ Wz0,
                             const float* __restrict__ Wh0, const float* __restrict__ Wr1,
                             const float* __restrict__ Wz1, const float* __restrict__ Wh1,
                             __half* __restrict__ dst) {
  int idx = blockIdx.x * blockDim.x + threadIdx.x;
  if (idx >= PACK_TOTAL) return;
  const float* src;
  int row0, local;
  if (idx < 73728) {
    int r = idx / 24576; local = idx % 24576;
    src = (r == 0) ? Wr0 : (r == 1) ? Wz0 : Wh0;
    row0 = 0;
  } else {
    int q = (idx - 73728) / 65536; local = (idx - 73728) % 65536;
    if (q < 3)      { src = (q == 0) ? Wr0 : (q == 1) ? Wz0 : Wh0; row0 = 96;  }
    else if (q < 6) { src = (q == 3) ? Wr1 : (q == 4) ? Wz1 : Wh1; row0 = 0;   }
    else            { src = (q == 6) ? Wr1 : (q == 7) ? Wz1 : Wh1; row0 = 256; }
  }
  int seg = local >> 13;
  int rem = local & 8191;
  int j   = rem >> 5;
  int s   = (rem >> 3) & 3;
  int i   = rem & 7;
  int row = row0 + seg * 32 + s * 8 + i;
  dst[idx] = __float2half(src[(size_t)row * HH + j]);
}

__device__ __forceinline__ float dot8(uint4 w, uint4 v, float acc) {
#if __has_builtin(__builtin_amdgcn_fdot2)
  union { uint4 u; half2_t h[4]; } W, V;
  W.u = w; V.u = v;
  acc = __builtin_amdgcn_fdot2(W.h[0], V.h[0], acc, false);
  acc = __builtin_amdgcn_fdot2(W.h[1], V.h[1], acc, false);
  acc = __builtin_amdgcn_fdot2(W.h[2], V.h[2], acc, false);
  acc = __builtin_amdgcn_fdot2(W.h[3], V.h[3], acc, false);
#else
  union { unsigned u; __half2 h; } cw, cv;
  float2 wf, vf;
  cw.u = w.x; cv.u = v.x; wf = __half22float2(cw.h); vf = __half22float2(cv.h);
  acc = fmaf(wf.x, vf.x, acc); acc = fmaf(wf.y, vf.y, acc);
  cw.u = w.y; cv.u = v.y; wf = __half22float2(cw.h); vf = __half22float2(cv.h);
  acc = fmaf(wf.x, vf.x, acc); acc = fmaf(wf.y, vf.y, acc);
  cw.u = w.z; cv.u = v.z; wf = __half22float2(cw.h); vf = __half22float2(cv.h);
  acc = fmaf(wf.x, vf.x, acc); acc = fmaf(wf.y, vf.y, acc);
  cw.u = w.w; cv.u = v.w; wf = __half22float2(cw.h); vf = __half22float2(cv.h);
  acc = fmaf(wf.x, vf.x, acc); acc = fmaf(wf.y, vf.y, acc);
#endif
  return acc;
}

__device__ __forceinline__ float kred(float a) {
  a += __shfl_xor(a, 1, 64);
  a += __shfl_xor(a, 2, 64);
  return a;
}

__device__ __forceinline__ float wsum64(float v) {
  #pragma unroll
  for (int o = 32; o > 0; o >>= 1) v += __shfl_xor(v, o, 64);
  return v;
}

__device__ __forceinline__ float rcpf(float v) {
#if __has_builtin(__builtin_amdgcn_rcpf)
  return __builtin_amdgcn_rcpf(v);
#else
  return 1.f / v;
#endif
}
__device__ __forceinline__ float sigm(float v) { return rcpf(1.f + __expf(-v)); }
__device__ __forceinline__ float tanh_fast(float v) {
  float t = __expf(-2.f * fabsf(v));              // (0,1]
  float r = (1.f - t) * rcpf(1.f + t);
  return copysignf(r, v);
}

// bounded exact-match spin on an agent-scope flag (0xAA poison never matches)
__device__ __forceinline__ void spin_eq(uint32_t* p, uint32_t want) {
  for (int it = 0; it < 1000000; ++it) {
    if (__hip_atomic_load(p, __ATOMIC_RELAXED, __HIP_MEMORY_SCOPE_AGENT) == want) return;
    __builtin_amdgcn_s_sleep(1);
  }
}

__global__ __launch_bounds__(1024)
__attribute__((amdgpu_waves_per_eu(4, 4)))
void grud_pipe(const float* __restrict__ x, const float* __restrict__ mask,
               const float* __restrict__ delta, const float* __restrict__ xl,
               const int* __restrict__ sidx, const float* __restrict__ emb,
               const float* __restrict__ gx0, const float* __restrict__ gh0,
               const float* __restrict__ br0, const float* __restrict__ bz0,
               const float* __restrict__ bh0, const float* __restrict__ br1,
               const float* __restrict__ bz1, const float* __restrict__ bh1,
               const float* __restrict__ Wp1, const float* __restrict__ bp1,
               const float* __restrict__ Wp2, const float* __restrict__ bp2,
               const __half* __restrict__ PW, uint32_t* wsu, float* __restrict__ out)
{
  const int bid = blockIdx.x;
  const bool isA = bid < 128;
  const int pair = isA ? bid : (bid - 128);
  const int tid = threadIdx.x;
  const int j = tid >> 2, s = tid & 3, s8 = s * 8, jb = j * 4 + s;

  uint32_t* msgbase = wsu + (MSG_OFF >> 2) + (size_t)pair * (RING * MSG_U32);
  uint32_t* flag    = wsu + (FLAG_OFF >> 2) + pair * RING;
  uint32_t* cflag   = wsu + (CFLAG_OFF >> 2) + pair * RING;

  __shared__ __align__(16) uint4  wlds[8192];   // 128 KiB: W0HH (A) / W1HH (B)
  __shared__ __align__(16) __half xfh[2][96];
  __shared__ __align__(16) __half hdech[2][256];
  __shared__ __align__(16) __half rhh[2][256];
  __shared__ __align__(16) __half h0h[2][256];
  __shared__ __align__(16) __half h0c[2][256];
  __shared__ __align__(16) __half h1h[2][256];
  __shared__ __align__(16) float  fbuf[2][256];
  __shared__ float p1f[256];

  if (isA) {
    const uint4* W0XR = (const uint4*)(PW + OFF_W0X_R);
    const uint4* W0XZ = (const uint4*)(PW + OFF_W0X_Z);
    const uint4* W0XH = (const uint4*)(PW + OFF_W0X_H);
    const uint4* W0HR = (const uint4*)(PW + OFF_W0H_R);
    const uint4* W0HZ = (const uint4*)(PW + OFF_W0H_Z);
    const uint4* W0HH = (const uint4*)(PW + OFF_W0H_H);
    const uint4* W1XH = (const uint4*)(PW + OFF_W1X_H);
    #pragma unroll 2
    for (int seg = 0; seg < 8; ++seg) wlds[seg * 1024 + jb] = W0HH[seg * 1024 + jb];

    const float brj0 = br0[j], bzj0 = bz0[j], bhj0 = bh0[j];
    const float gh0j = gh0[j];
    float h0j0 = 0.f, h0j1 = 0.f;
    if (tid < 64)  { int g = tid >> 5, e = tid & 31;
                     xfh[g][DX + e] = __float2half(emb[(size_t)sidx[2 * pair + g] * EE + e]); }
    float gx0k = 0.f;
    if (tid < 128) gx0k = gx0[tid & 63];
    const size_t xb0 = (size_t)(2 * pair) * TT * DX, xb1 = (size_t)(2 * pair + 1) * TT * DX;
    float xv = 0, mv = 0, dv = 0, xlv = 0;
    if (tid < 128) { size_t a = (tid < 64 ? xb0 : xb1) + (tid & 63);
                     xv = x[a]; mv = mask[a]; dv = delta[a]; xlv = xl[a]; }
    __syncthreads();

    for (int t = 0; t < TT; ++t) {
      const int slot = t & (RING - 1);
      if (tid == 0 && t >= RING) spin_eq(&cflag[slot], (uint32_t)(t - RING + 1));
      // early-issue x-part weight loads (drained by the merged barrier below,
      // latency hidden under P0 compute)
      uint4 a0 = W0XR[jb], a1 = W0XR[1024 + jb], a2 = W0XR[2048 + jb];
      uint4 a3 = W0XZ[jb], a4 = W0XZ[1024 + jb], a5 = W0XZ[2048 + jb];
      uint4 a6 = W0XH[jb], a7 = W0XH[1024 + jb], a8 = W0XH[2048 + jb];
      // P0: x_filled (threads<128, prefetched regs)
      if (tid < 128) {
        float xd = __expf(-fmaxf(dv * gx0k, 0.f)) * xlv;
        xfh[tid >> 6][tid & 63] = __float2half(mv > 0.f ? xv : xd);
      }
      // P1 merged: redundant per-wave mean-delta (broadcast loads, L1-served)
      {
        size_t dofs = (size_t)t * DX + (tid & 63);
        float sd0 = wsum64(delta[xb0 + dofs]) * (1.f / 96.f);
        float sd1 = wsum64(delta[xb1 + dofs]) * (1.f / 96.f);
        float hd0 = __expf(-fmaxf(sd0 * gh0j, 0.f)) * h0j0;
        float hd1 = __expf(-fmaxf(sd1 * gh0j, 0.f)) * h0j1;
        if (s == 0) { hdech[0][j] = __float2half(hd0); hdech[1][j] = __float2half(hd1); }
        // stash for update step
        fbuf[0][j] = hd0;  // only s==0's value matters; benign replicated write
        fbuf[1][j] = hd1;
      }
      __syncthreads();
      float hd0 = fbuf[0][j], hd1 = fbuf[1][j];
      // prefetch next-t inputs (in flight under P2 dots)
      if (tid < 128 && t + 1 < TT) {
        size_t a = (tid < 64 ? xb0 : xb1) + (size_t)(t + 1) * DX + (tid & 63);
        xv = x[a]; mv = mask[a]; dv = delta[a]; xlv = xl[a];
      }
      // P2: x-part gates from early-loaded regs; h-part streamed
      float ar0 = 0, ar1v = 0, az0 = 0, az1v = 0, ah0 = 0, ah1v = 0;
      {
        uint4 v00 = *(const uint4*)(&xfh[0][s8]);
        uint4 v01 = *(const uint4*)(&xfh[0][32 + s8]);
        uint4 v02 = *(const uint4*)(&xfh[0][64 + s8]);
        uint4 v10 = *(const uint4*)(&xfh[1][s8]);
        uint4 v11 = *(const uint4*)(&xfh[1][32 + s8]);
        uint4 v12 = *(const uint4*)(&xfh[1][64 + s8]);
        ar0 = dot8(a0, v00, ar0); ar0 = dot8(a1, v01, ar0); ar0 = dot8(a2, v02, ar0);
        ar1v = dot8(a0, v10, ar1v); ar1v = dot8(a1, v11, ar1v); ar1v = dot8(a2, v12, ar1v);
        az0 = dot8(a3, v00, az0); az0 = dot8(a4, v01, az0); az0 = dot8(a5, v02, az0);
        az1v = dot8(a3, v10, az1v); az1v = dot8(a4, v11, az1v); az1v = dot8(a5, v12, az1v);
        ah0 = dot8(a6, v00, ah0); ah0 = dot8(a7, v01, ah0); ah0 = dot8(a8, v02, ah0);
        ah1v = dot8(a6, v10, ah1v); ah1v = dot8(a7, v11, ah1v); ah1v = dot8(a8, v12, ah1v);
      }
      #pragma unroll 2
      for (int seg = 0; seg < 8; ++seg) {
        uint4 v0 = *(const uint4*)(&hdech[0][seg * 32 + s8]);
        uint4 v1 = *(const uint4*)(&hdech[1][seg * 32 + s8]);
        uint4 wr = W0HR[seg * 1024 + jb], wz = W0HZ[seg * 1024 + jb];
        ar0 = dot8(wr, v0, ar0); ar1v = dot8(wr, v1, ar1v);
        az0 = dot8(wz, v0, az0); az1v = dot8(wz, v1, az1v);
      }
      ar0 = kred(ar0) + brj0; ar1v = kred(ar1v) + brj0;
      az0 = kred(az0) + bzj0; az1v = kred(az1v) + bzj0;
      float r0 = sigm(ar0), r1g = sigm(ar1v), z0 = sigm(az0), z1g = sigm(az1v);
      if (s == 0) { rhh[0][j] = __float2half(r0 * hd0); rhh[1][j] = __float2half(r1g * hd1); }
      __syncthreads();
      // P3: h_tilde from LDS-resident W0HH; h0 update
      #pragma unroll 2
      for (int seg = 0; seg < 8; ++seg) {
        uint4 w  = wlds[seg * 1024 + jb];
        uint4 v0 = *(const uint4*)(&rhh[0][seg * 32 + s8]);
        uint4 v1 = *(const uint4*)(&rhh[1][seg * 32 + s8]);
        ah0 = dot8(w, v0, ah0); ah1v = dot8(w, v1, ah1v);
      }
      ah0 = kred(ah0) + bhj0; ah1v = kred(ah1v) + bhj0;
      h0j0 = (1.f - z0) * hd0 + z0 * tanh_fast(ah0);
      h0j1 = (1.f - z1g) * hd1 + z1g * tanh_fast(ah1v);
      if (s == 0) { h0h[0][j] = __float2half(h0j0); h0h[1][j] = __float2half(h0j1); }
      __syncthreads();
      // P3b: ah1x = W1XH . h0 (fp32 partial for B)
      float ax0 = 0.f, ax1 = 0.f;
      #pragma unroll 2
      for (int seg = 0; seg < 8; ++seg) {
        uint4 w  = W1XH[seg * 1024 + jb];
        uint4 v0 = *(const uint4*)(&h0h[0][seg * 32 + s8]);
        uint4 v1 = *(const uint4*)(&h0h[1][seg * 32 + s8]);
        ax0 = dot8(w, v0, ax0); ax1 = dot8(w, v1, ax1);
      }
      ax0 = kred(ax0); ax1 = kred(ax1);
      uint32_t* msg = msgbase + slot * MSG_U32;
      if (s == 0) {
        __hip_atomic_store(msg + 256 + j, __float_as_uint(ax0), __ATOMIC_RELAXED, __HIP_MEMORY_SCOPE_AGENT);
        __hip_atomic_store(msg + 512 + j, __float_as_uint(ax1), __ATOMIC_RELAXED, __HIP_MEMORY_SCOPE_AGENT);
      }
      if (tid < 256)
        __hip_atomic_store(msg + tid, ((const uint32_t*)h0h)[tid], __ATOMIC_RELAXED, __HIP_MEMORY_SCOPE_AGENT);
      __syncthreads();   // vmcnt drained before barrier -> stores complete
      if (tid == 0)
        __hip_atomic_store(&flag[slot], (uint32_t)(t + 1), __ATOMIC_RELAXED, __HIP_MEMORY_SCOPE_AGENT);
    }
  } else {
    const uint4* W1XR = (const uint4*)(PW + OFF_W1X_R);
    const uint4* W1XZ = (const uint4*)(PW + OFF_W1X_Z);
    const uint4* W1HR = (const uint4*)(PW + OFF_W1H_R);
    const uint4* W1HZ = (const uint4*)(PW + OFF_W1H_Z);
    const uint4* W1HH = (const uint4*)(PW + OFF_W1H_H);
    #pragma unroll 2
    for (int seg = 0; seg < 8; ++seg) wlds[seg * 1024 + jb] = W1HH[seg * 1024 + jb];
    const float brj1 = br1[j], bzj1 = bz1[j], bhj1 = bh1[j];
    float h1j0 = 0.f, h1j1 = 0.f;
    if (tid < 512) { int g = tid >> 8, k = tid & 255; h1h[g][k] = __float2half(0.f); }

    for (int t = 0; t < TT; ++t) {
      const int slot = t & (RING - 1);
      __syncthreads();   // h1h(t-1) visible; msg buffers reusable
      // h-part gates FIRST (no msg dependency; overlaps A's production)
      float ar0 = 0, ar1v = 0, az0 = 0, az1v = 0;
      #pragma unroll 2
      for (int seg = 0; seg < 8; ++seg) {
        uint4 v0 = *(const uint4*)(&h1h[0][seg * 32 + s8]);
        uint4 v1 = *(const uint4*)(&h1h[1][seg * 32 + s8]);
        uint4 whr = W1HR[seg * 1024 + jb], whz = W1HZ[seg * 1024 + jb];
        ar0 = dot8(whr, v0, ar0); ar1v = dot8(whr, v1, ar1v);
        az0 = dot8(whz, v0, az0); az1v = dot8(whz, v1, az1v);
      }
      if (tid == 0) spin_eq(&flag[slot], (uint32_t)(t + 1));
      __syncthreads();
      uint32_t* msg = msgbase + slot * MSG_U32;
      if (tid < 256)
        ((uint32_t*)h0c)[tid] = __hip_atomic_load(msg + tid, __ATOMIC_RELAXED, __HIP_MEMORY_SCOPE_AGENT);
      else if (tid < 768) {
        int idx = tid - 256;
        fbuf[idx >> 8][idx & 255] =
            __uint_as_float(__hip_atomic_load(msg + tid, __ATOMIC_RELAXED, __HIP_MEMORY_SCOPE_AGENT));
      }
      __syncthreads();
      if (tid == 0)
        __hip_atomic_store(&cflag[slot], (uint32_t)(t + 1), __ATOMIC_RELAXED, __HIP_MEMORY_SCOPE_AGENT);
      // x-part gates vs received h0
      #pragma unroll 2
      for (int seg = 0; seg < 8; ++seg) {
        uint4 u0 = *(const uint4*)(&h0c[0][seg * 32 + s8]);
        uint4 u1 = *(const uint4*)(&h0c[1][seg * 32 + s8]);
        uint4 wxr = W1XR[seg * 1024 + jb], wxz = W1XZ[seg * 1024 + jb];
        ar0 = dot8(wxr, u0, ar0); ar1v = dot8(wxr, u1, ar1v);
        az0 = dot8(wxz, u0, az0); az1v = dot8(wxz, u1, az1v);
      }
      ar0 = kred(ar0) + brj1; ar1v = kred(ar1v) + brj1;
      az0 = kred(az0) + bzj1; az1v = kred(az1v) + bzj1;
      float r0 = sigm(ar0), r1g = sigm(ar1v), z0 = sigm(az0), z1g = sigm(az1v);
      if (s == 0) { rhh[0][j] = __float2half(r0 * h1j0); rhh[1][j] = __float2half(r1g * h1j1); }
      __syncthreads();
      // P5: h_tilde = ah1x (from A) + W1HH(LDS).rhh ; h1 update
      float p0 = 0.f, p1 = 0.f;
      #pragma unroll 2
      for (int seg = 0; seg < 8; ++seg) {
        uint4 w  = wlds[seg * 1024 + jb];
        uint4 v0 = *(const uint4*)(&rhh[0][seg * 32 + s8]);
        uint4 v1 = *(const uint4*)(&rhh[1][seg * 32 + s8]);
        p0 = dot8(w, v0, p0); p1 = dot8(w, v1, p1);
      }
      p0 = kred(p0); p1 = kred(p1);
      float ahf0 = fbuf[0][j] + p0 + bhj1;
      float ahf1 = fbuf[1][j] + p1 + bhj1;
      h1j0 = (1.f - z0) * h1j0 + z0 * tanh_fast(ahf0);
      h1j1 = (1.f - z1g) * h1j1 + z1g * tanh_fast(ahf1);
      if (s == 0) { h1h[0][j] = __float2half(h1j0); h1h[1][j] = __float2half(h1j1); }
    }

    // head for both batches (fp32)
    __syncthreads();
    if (s == 0) { fbuf[0][j] = h1j0; fbuf[1][j] = h1j1; }
    __syncthreads();
    for (int g = 0; g < 2; ++g) {
      float a1 = 0.f; int k0 = s * 64;
      #pragma unroll 8
      for (int k = 0; k < 64; ++k) a1 = fmaf(fbuf[g][k0 + k], Wp1[(size_t)(k0 + k) * HH + j], a1);
      a1 = kred(a1) + bp1[j];
      if (s == 0) p1f[j] = fmaxf(a1, 0.f);
      __syncthreads();
      if (tid < 192) {
        int jo = tid >> 2, so = tid & 3; float o = 0.f; int kk0 = so * 64;
        #pragma unroll 8
        for (int k = 0; k < 64; ++k) o = fmaf(p1f[kk0 + k], Wp2[(size_t)(kk0 + k) * 48 + jo], o);
        o += __shfl_xor(o, 1, 64);
        o += __shfl_xor(o, 2, 64);
        if (so == 0) out[(size_t)(2 * pair + g) * 48 + jo] = o + bp2[jo];
      }
      __syncthreads();
    }
  }
}

extern "C" void kernel_launch(void* const* d_in, const int* in_sizes, int n_in,
                              void* d_out, int out_size, void* d_ws, size_t ws_size,
                              hipStream_t stream) {
  const float* x    = (const float*)d_in[0];
  const float* mask = (const float*)d_in[1];
  const float* delta= (const float*)d_in[2];
  const float* xl   = (const float*)d_in[3];
  const int*   sidx = (const int*)d_in[4];
  const float* emb  = (const float*)d_in[5];
  const float* gx0  = (const float*)d_in[6];
  const float* gh0  = (const float*)d_in[7];
  const float* Wr0  = (const float*)d_in[8];
  const float* br0  = (const float*)d_in[9];
  const float* Wz0  = (const float*)d_in[10];
  const float* bz0  = (const float*)d_in[11];
  const float* Wh0  = (const float*)d_in[12];
  const float* bh0  = (const float*)d_in[13];
  // d_in[14]=gx1, d_in[15]=gh1: mathematically inert (layer1 delta==0)
  const float* Wr1  = (const float*)d_in[16];
  const float* br1  = (const float*)d_in[17];
  const float* Wz1  = (const float*)d_in[18];
  const float* bz1  = (const float*)d_in[19];
  const float* Wh1  = (const float*)d_in[20];
  const float* bh1  = (const float*)d_in[21];
  const float* Wp1  = (const float*)d_in[22];
  const float* bp1  = (const float*)d_in[23];
  const float* Wp2  = (const float*)d_in[24];
  const float* bp2  = (const float*)d_in[25];
  __half*   PW  = (__half*)d_ws;
  uint32_t* wsu = (uint32_t*)d_ws;
  float* out = (float*)d_out;

  hipLaunchKernelGGL(pack_weights, dim3((PACK_TOTAL + 255) / 256), dim3(256), 0, stream,
                     Wr0, Wz0, Wh0, Wr1, Wz1, Wh1, PW);
  hipLaunchKernelGGL(grud_pipe, dim3(BB), dim3(1024), 0, stream,
                     x, mask, delta, xl, sidx, emb, gx0, gh0,
                     br0, bz0, bh0, br1, bz1, bh1, Wp1, bp1, Wp2, bp2, PW, wsu, out);
}